// Round 3
// baseline (2331.314 us; speedup 1.0000x reference)
//
#include <hip/hip_runtime.h>

#define NS 0.2f  // leaky_relu negative slope

// ===================== CSR construction =====================
__global__ void k_deg(const int* __restrict__ dst, int* degi, int E){
  int stride = gridDim.x * blockDim.x;
  for(int e = blockIdx.x * blockDim.x + threadIdx.x; e < E; e += stride)
    atomicAdd(&degi[dst[e]], 1);
}

__device__ __forceinline__ int wave_iscan(int v, int lane){
  #pragma unroll
  for(int o = 1; o < 64; o <<= 1){
    int t = __shfl_up(v, o);
    if(lane >= o) v += t;
  }
  return v;
}

__global__ void k_scan(const int* __restrict__ deg, int* __restrict__ rowoff, int n){
  __shared__ int wsum[16];
  __shared__ int carry_s;
  const int lane = threadIdx.x & 63;
  const int w = threadIdx.x >> 6;
  if(threadIdx.x == 0) carry_s = 0;
  __syncthreads();
  for(int base = 0; base < n; base += 1024){
    int idx = base + (int)threadIdx.x;
    int v = (idx < n) ? deg[idx] : 0;
    int inc = wave_iscan(v, lane);
    if(lane == 63) wsum[w] = inc;
    __syncthreads();
    if(w == 0){
      int s = (lane < 16) ? wsum[lane] : 0;
      s = wave_iscan(s, lane);
      if(lane < 16) wsum[lane] = s;
    }
    __syncthreads();
    int woff = (w > 0) ? wsum[w - 1] : 0;
    int total = wsum[15];
    if(idx < n) rowoff[idx] = carry_s + woff + inc - v;
    __syncthreads();
    if(threadIdx.x == 0) carry_s += total;
    __syncthreads();
  }
  if(threadIdx.x == 0) rowoff[n] = carry_s;
}

__global__ void k_fill(const int* __restrict__ dst, int* pos, int* eidx, int E){
  int stride = gridDim.x * blockDim.x;
  for(int e = blockIdx.x * blockDim.x + threadIdx.x; e < E; e += stride){
    int slot = atomicAdd(&pos[dst[e]], 1);
    eidx[slot] = e;
  }
}

// ===================== tiled GEMM: C = A @ W^T + b =====================
#define BM 64
#define BN 64
#define BK 16
__global__ __launch_bounds__(256) void k_gemm(
    const float* __restrict__ A, const float* __restrict__ W,
    const float* __restrict__ b, float* __restrict__ C,
    int n, int K, int M, int dorelu)
{
  __shared__ float As[BM][BK + 1];
  __shared__ float Bs[BN][BK + 1];
  const int bi = blockIdx.x * BM;
  const int bj = blockIdx.y * BN;
  const int tid = threadIdx.x;
  const int tr = tid / 16, tc = tid % 16;
  float acc[4][4] = {};
  for(int k0 = 0; k0 < K; k0 += BK){
    for(int l = tid; l < BM * BK; l += 256){
      int r = l / BK, c = l % BK;
      int gr = bi + r, gc = k0 + c;
      As[r][c] = (gr < n && gc < K) ? A[(long)gr * K + gc] : 0.0f;
    }
    for(int l = tid; l < BN * BK; l += 256){
      int r = l / BK, c = l % BK;
      int gr = bj + r, gc = k0 + c;
      Bs[r][c] = (gr < M && gc < K) ? W[(long)gr * K + gc] : 0.0f;
    }
    __syncthreads();
    #pragma unroll
    for(int kk = 0; kk < BK; ++kk){
      float av[4], bv[4];
      #pragma unroll
      for(int r = 0; r < 4; r++) av[r] = As[tr * 4 + r][kk];
      #pragma unroll
      for(int c = 0; c < 4; c++) bv[c] = Bs[tc * 4 + c][kk];
      #pragma unroll
      for(int r = 0; r < 4; r++)
        #pragma unroll
        for(int c = 0; c < 4; c++) acc[r][c] += av[r] * bv[c];
    }
    __syncthreads();
  }
  for(int r = 0; r < 4; r++){
    int gr = bi + tr * 4 + r;
    if(gr >= n) continue;
    for(int c = 0; c < 4; c++){
      int gc = bj + tc * 4 + c;
      if(gc >= M) continue;
      float val = acc[r][c] + b[gc];
      C[(long)gr * M + gc] = dorelu ? fmaxf(val, 0.0f) : val;
    }
  }
}

static void gemm_launch(const float* A, const float* W, const float* b, float* C,
                        int n, int K, int M, int relu, hipStream_t s){
  dim3 grid((n + BM - 1) / BM, (M + BN - 1) / BN);
  k_gemm<<<grid, 256, 0, s>>>(A, W, b, C, n, K, M, relu);
}

// ===================== edge logits: one THREAD per edge, natural order =====================
// logits[e] = att . leaky_relu( xl[src] + xr[dst] + We @ ea[e] )
__global__ __launch_bounds__(256) void k_edge_logits(
    const float* __restrict__ xl, const float* __restrict__ xr,
    const float* __restrict__ ea,
    const int* __restrict__ src, const int* __restrict__ dst,
    const float* __restrict__ We, const float* __restrict__ att,
    float* __restrict__ logits, int E, int F)
{
  __shared__ float4 sWe[200 * 5];   // F rows padded to 20 floats (5 x float4)
  __shared__ float sAtt[256];
  const int tid = threadIdx.x;
  for(int idx = tid; idx < F * 5; idx += 256){
    int f = idx / 5, q = idx % 5;
    int k0 = q * 4;
    float4 v;
    v.x = (k0 + 0 < 18) ? We[f * 18 + k0 + 0] : 0.0f;
    v.y = (k0 + 1 < 18) ? We[f * 18 + k0 + 1] : 0.0f;
    v.z = (k0 + 2 < 18) ? We[f * 18 + k0 + 2] : 0.0f;
    v.w = (k0 + 3 < 18) ? We[f * 18 + k0 + 3] : 0.0f;
    sWe[idx] = v;
  }
  for(int f = tid; f < F; f += 256) sAtt[f] = att[f];
  __syncthreads();

  int e = blockIdx.x * 256 + tid;
  if(e >= E) return;
  int s = src[e], d = dst[e];
  float eav[20];
  #pragma unroll
  for(int k = 0; k < 18; k++) eav[k] = ea[(long)e * 18 + k];
  eav[18] = 0.0f; eav[19] = 0.0f;
  const float4* xls = (const float4*)(xl + (long)s * F);
  const float4* xrd = (const float4*)(xr + (long)d * F);
  float acc = 0.0f;
  for(int fq = 0; fq < F / 4; ++fq){
    float4 a = xls[fq], b = xrd[fq];
    float tv[4] = {a.x + b.x, a.y + b.y, a.z + b.z, a.w + b.w};
    #pragma unroll
    for(int c = 0; c < 4; c++){
      int f = fq * 4 + c;
      float t = tv[c];
      #pragma unroll
      for(int q = 0; q < 5; q++){
        float4 wq = sWe[f * 5 + q];
        t = fmaf(wq.x, eav[4 * q + 0], t);
        t = fmaf(wq.y, eav[4 * q + 1], t);
        t = fmaf(wq.z, eav[4 * q + 2], t);
        t = fmaf(wq.w, eav[4 * q + 3], t);
      }
      t = (t > 0.0f) ? t : NS * t;
      acc = fmaf(sAtt[f], t, acc);
    }
  }
  logits[e] = acc;
}

// ===================== node softmax + aggregate: one WAVE per node =====================
// Computes ea_mean + self logit inline, chunked online softmax over precomputed
// edge logits, then feature-parallel gather-aggregate. Zero atomics, no syncthreads.
#define CH 128
template<int JMAX>
__global__ __launch_bounds__(256) void k_gat_agg(
    const float* __restrict__ xl, const float* __restrict__ xr,
    const float* __restrict__ ea, const int* __restrict__ src,
    const int* __restrict__ rowoff, const int* __restrict__ eidx,
    const float* __restrict__ logits,
    const float* __restrict__ We, const float* __restrict__ att,
    const float* __restrict__ bias, float* __restrict__ out,
    int n, int F, int dorelu)
{
  const int lane = threadIdx.x & 63;
  const int wid  = threadIdx.x >> 6;
  __shared__ float  s_eam[4][20];
  __shared__ float2 s_ws[4][CH];   // {logit->weight, src as float bits}
  const int i = blockIdx.x * 4 + wid;
  if(i >= n) return;          // wave-uniform exit; no __syncthreads below
  const int r0 = rowoff[i], r1 = rowoff[i + 1];
  const int deg = r1 - r0;

  // ---- ea_mean for self-loop ----
  if(lane < 20){
    float ssum = 0.0f;
    if(lane < 18)
      for(int p = r0; p < r1; ++p) ssum += ea[(long)eidx[p] * 18 + lane];
    s_eam[wid][lane] = (lane < 18) ? ssum / fmaxf((float)deg, 1.0f) : 0.0f;
  }

  // ---- self logit (feature-parallel) + cache xl[i] ----
  float selfl = 0.0f;
  float xiv[JMAX];
  #pragma unroll
  for(int j = 0; j < JMAX; ++j){
    int f = lane + j * 64;
    xiv[j] = 0.0f;
    if(f < F){
      float xv = xl[(long)i * F + f];
      xiv[j] = xv;
      float t = xv + xr[(long)i * F + f];
      const float* w = We + f * 18;
      #pragma unroll
      for(int k = 0; k < 18; k++) t = fmaf(w[k], s_eam[wid][k], t);
      t = (t > 0.0f) ? t : NS * t;
      selfl = fmaf(att[f], t, selfl);
    }
  }
  #pragma unroll
  for(int o = 32; o; o >>= 1) selfl += __shfl_xor(selfl, o);

  // ---- online softmax init with self-loop (weight 1 at m = selfl) ----
  float m = selfl, denom = 1.0f;
  float acc[JMAX];
  #pragma unroll
  for(int j = 0; j < JMAX; ++j) acc[j] = xiv[j];

  // ---- chunks of incident edges ----
  for(int c0 = 0; c0 < deg; c0 += CH){
    int cn = min(CH, deg - c0);
    // lane-parallel: load eidx -> logit, src; stash in LDS
    float lmax = -3.4e38f;
    for(int q = lane; q < cn; q += 64){
      int e = eidx[r0 + c0 + q];
      float l = logits[e];
      int s = src[e];
      s_ws[wid][q] = make_float2(l, __int_as_float(s));
      lmax = fmaxf(lmax, l);
    }
    #pragma unroll
    for(int o = 32; o; o >>= 1) lmax = fmaxf(lmax, __shfl_xor(lmax, o));
    float newm = fmaxf(m, lmax);
    float scale = expf(m - newm);
    denom *= scale;
    #pragma unroll
    for(int j = 0; j < JMAX; ++j) acc[j] *= scale;
    m = newm;
    // lane-parallel: weights
    float psum = 0.0f;
    for(int q = lane; q < cn; q += 64){
      float2 ws = s_ws[wid][q];
      float w = expf(ws.x - m);
      s_ws[wid][q].x = w;
      psum += w;
    }
    #pragma unroll
    for(int o = 32; o; o >>= 1) psum += __shfl_xor(psum, o);
    denom += psum;
    // serial over chunk, feature-parallel gather-aggregate
    for(int p = 0; p < cn; ++p){
      float2 ws = s_ws[wid][p];
      float w = ws.x;
      int s = __float_as_int(ws.y);
      const float* xs = xl + (long)s * F;
      #pragma unroll
      for(int j = 0; j < JMAX; ++j){
        int f = lane + j * 64;
        if(f < F) acc[j] = fmaf(w, xs[f], acc[j]);
      }
    }
  }

  // ---- write ----
  float inv = 1.0f / denom;
  #pragma unroll
  for(int j = 0; j < JMAX; ++j){
    int f = lane + j * 64;
    if(f < F){
      float o = acc[j] * inv + bias[f];
      out[(long)i * F + f] = dorelu ? fmaxf(o, 0.0f) : o;
    }
  }
}

// ===================== rule pooling (rule_batch sorted) =====================
__global__ void k_rule_starts(const int* __restrict__ rb, int* starts, int NR, int R){
  int r = blockIdx.x * blockDim.x + threadIdx.x;
  if(r > R) return;
  if(r == R){ starts[R] = NR; return; }
  int lo = 0, hi = NR;
  while(lo < hi){ int mid = (lo + hi) >> 1; if(rb[mid] < r) lo = mid + 1; else hi = mid; }
  starts[r] = lo;
}

__global__ void k_pool_rules(const float* __restrict__ h, const int* __restrict__ starts,
                             float* __restrict__ y, int R, int F){
  long idx = (long)blockIdx.x * blockDim.x + threadIdx.x;
  long total = (long)R * F;
  if(idx >= total) return;
  int r = (int)(idx / F);
  int f = (int)(idx % F);
  int s0 = starts[r], s1 = starts[r + 1];
  float a = 0.0f;
  for(int i = s0; i < s1; i++) a += h[(long)i * F + f];
  y[idx] = a / fmaxf((float)(s1 - s0), 1.0f);
}

// ===================== global mean + bilinear =====================
__global__ void k_pool_all(const float* __restrict__ g, float* xp, long total4, int F){
  __shared__ float s[128];
  for(int j = threadIdx.x; j < F; j += blockDim.x) s[j] = 0.0f;
  __syncthreads();
  long stride = (long)gridDim.x * blockDim.x;
  const float4* g4 = (const float4*)g;
  for(long idx = (long)blockIdx.x * blockDim.x + threadIdx.x; idx < total4; idx += stride){
    float4 v = g4[idx];
    long base = idx * 4;
    atomicAdd(&s[(int)((base + 0) % F)], v.x);
    atomicAdd(&s[(int)((base + 1) % F)], v.y);
    atomicAdd(&s[(int)((base + 2) % F)], v.z);
    atomicAdd(&s[(int)((base + 3) % F)], v.w);
  }
  __syncthreads();
  for(int j = threadIdx.x; j < F; j += blockDim.x){
    float v = s[j];
    if(v != 0.0f) atomicAdd(&xp[j], v);
  }
}

__global__ void k_bil_v(const float* __restrict__ xp, const float* __restrict__ Wb,
                        float* v, float inv_n){
  int e = threadIdx.x;
  if(e < 100){
    float a = 0.0f;
    for(int d = 0; d < 100; d++) a += xp[d] * Wb[d * 100 + e];
    v[e] = a * inv_n;
  }
}

__global__ void k_bil_out(const float* __restrict__ v, const float* __restrict__ y,
                          const float* __restrict__ bilb, float* out, int R){
  int r = blockIdx.x * blockDim.x + threadIdx.x;
  if(r < R){
    float a = 0.0f;
    const float* yr = y + (long)r * 100;
    for(int e = 0; e < 100; e++) a += v[e] * yr[e];
    out[r] = a + bilb[0];
  }
}

// ------------------------------------------------------------------
static inline int nblk(long n){
  long b = (n + 255) / 256;
  if(b > 20480) b = 20480;
  if(b < 1) b = 1;
  return (int)b;
}

struct GatParams { const float *Wl,*bl,*Wr,*br,*We,*att,*b; };

// full GATv2 layer with the new split kernels
static void run_gatv2(const float* x, int fin, int fout, int n,
                      const int* src, const int* dst, const float* ea, int E,
                      GatParams P, float* out, int dorelu,
                      float* xl, float* xr, float* logits,
                      const int* rowoff, const int* eidx, hipStream_t stream){
  gemm_launch(x, P.Wl, P.bl, xl, n, fin, fout, 0, stream);
  gemm_launch(x, P.Wr, P.br, xr, n, fin, fout, 0, stream);
  k_edge_logits<<<(E + 255) / 256, 256, 0, stream>>>(xl, xr, ea, src, dst,
                                                     P.We, P.att, logits, E, fout);
  if(fout <= 128)
    k_gat_agg<2><<<(n + 3) / 4, 256, 0, stream>>>(xl, xr, ea, src, rowoff, eidx, logits,
                                                  P.We, P.att, P.b, out, n, fout, dorelu);
  else
    k_gat_agg<4><<<(n + 3) / 4, 256, 0, stream>>>(xl, xr, ea, src, rowoff, eidx, logits,
                                                  P.We, P.att, P.b, out, n, fout, dorelu);
}

extern "C" void kernel_launch(void* const* d_in, const int* in_sizes, int n_in,
                              void* d_out, int out_size, void* d_ws, size_t ws_size,
                              hipStream_t stream){
  const float* x   = (const float*)d_in[0];
  const float* ea  = (const float*)d_in[1];
  const float* rx  = (const float*)d_in[2];
  const float* rea = (const float*)d_in[3];
  GatParams g0{ (const float*)d_in[4],  (const float*)d_in[5],  (const float*)d_in[6],
                (const float*)d_in[7],  (const float*)d_in[8],  (const float*)d_in[9],
                (const float*)d_in[10] };
  GatParams g1{ (const float*)d_in[11], (const float*)d_in[12], (const float*)d_in[13],
                (const float*)d_in[14], (const float*)d_in[15], (const float*)d_in[16],
                (const float*)d_in[17] };
  GatParams g2{ (const float*)d_in[18], (const float*)d_in[19], (const float*)d_in[20],
                (const float*)d_in[21], (const float*)d_in[22], (const float*)d_in[23],
                (const float*)d_in[24] };
  const float* lin_W = (const float*)d_in[25]; const float* lin_b = (const float*)d_in[26];
  const float* f1_W  = (const float*)d_in[27]; const float* f1_b  = (const float*)d_in[28];
  const float* f2_W  = (const float*)d_in[29]; const float* f2_b  = (const float*)d_in[30];
  const float* f3_W  = (const float*)d_in[31]; const float* f3_b  = (const float*)d_in[32];
  const float* bilW  = (const float*)d_in[33]; const float* bilb  = (const float*)d_in[34];
  const int* ei  = (const int*)d_in[35];
  const int* rei = (const int*)d_in[37];
  const int* rb  = (const int*)d_in[38];

  const int N  = in_sizes[0] / 16;
  const int E  = in_sizes[1] / 18;
  const int NR = in_sizes[2] / 16;
  const int ER = in_sizes[3] / 18;
  const int R  = out_size;

  float* Wf = (float*)d_ws;
  size_t off = 0;
  auto alloc  = [&](size_t nf){ float* p = Wf + off; off += nf; return p; };
  auto alloci = [&](size_t ni){ int* p = (int*)(Wf + off); off += ni; return p; };

  // persistent head
  float* y0 = alloc((size_t)R * 400);
  float* y1 = alloc((size_t)R * 200);
  float* y2 = alloc((size_t)R * 100);
  float* y3 = alloc((size_t)R * 100);
  float* xp = alloc(128);
  float* v  = alloc(128);
  int* starts = alloci(R + 1);
  const size_t arena = off;

  // ================= rule path =================
  {
    off = arena;
    float* h1 = alloc((size_t)NR * 100);
    float* h2 = alloc((size_t)NR * 200);
    float* xl = alloc((size_t)NR * 200);
    float* xr = alloc((size_t)NR * 200);
    float* logits = alloc(ER);
    int* rowoff = alloci(NR + 1);
    int* degi   = alloci(NR);
    int* pos    = alloci(NR);
    int* eidx   = alloci(ER);
    const int* rsrc = rei; const int* rdst = rei + ER;

    hipMemsetAsync(degi, 0, (size_t)NR * 4, stream);
    k_deg<<<nblk(ER), 256, 0, stream>>>(rdst, degi, ER);
    k_scan<<<1, 1024, 0, stream>>>(degi, rowoff, NR);
    hipMemcpyAsync(pos, rowoff, (size_t)NR * 4, hipMemcpyDeviceToDevice, stream);
    k_fill<<<nblk(ER), 256, 0, stream>>>(rdst, pos, eidx, ER);

    run_gatv2(rx, 16, 100, NR, rsrc, rdst, rea, ER, g1, h1, 1,
              xl, xr, logits, rowoff, eidx, stream);
    run_gatv2(h1, 100, 200, NR, rsrc, rdst, rea, ER, g2, h2, 1,
              xl, xr, logits, rowoff, eidx, stream);

    float* hlin = xl;  // NR*400 floats (xl+xr contiguous)
    gemm_launch(h2, lin_W, lin_b, hlin, NR, 200, 400, 0, stream);

    k_rule_starts<<<(R + 256) / 256, 256, 0, stream>>>(rb, starts, NR, R);
    k_pool_rules<<<nblk((long)R * 400), 256, 0, stream>>>(hlin, starts, y0, R, 400);

    gemm_launch(y0, f1_W, f1_b, y1, R, 400, 200, 1, stream);
    gemm_launch(y1, f2_W, f2_b, y2, R, 200, 100, 1, stream);
    gemm_launch(y2, f3_W, f3_b, y3, R, 100, 100, 0, stream);
  }

  // ================= data path =================
  {
    off = arena;
    float* g  = alloc((size_t)N * 100);
    float* xl = alloc((size_t)N * 100);
    float* xr = alloc((size_t)N * 100);
    float* logits = alloc(E);
    int* rowoff = alloci((size_t)N + 1);
    int* degi   = alloci(N);
    int* pos    = alloci(N);
    int* eidx   = alloci(E);
    const int* srcp = ei; const int* dstp = ei + E;

    hipMemsetAsync(degi, 0, (size_t)N * 4, stream);
    k_deg<<<nblk(E), 256, 0, stream>>>(dstp, degi, E);
    k_scan<<<1, 1024, 0, stream>>>(degi, rowoff, N);
    hipMemcpyAsync(pos, rowoff, (size_t)N * 4, hipMemcpyDeviceToDevice, stream);
    k_fill<<<nblk(E), 256, 0, stream>>>(dstp, pos, eidx, E);

    run_gatv2(x, 16, 100, N, srcp, dstp, ea, E, g0, g, 0,
              xl, xr, logits, rowoff, eidx, stream);

    hipMemsetAsync(xp, 0, 128 * 4, stream);
    k_pool_all<<<nblk((long)N * 25), 256, 0, stream>>>(g, xp, (long)N * 25, 100);
    k_bil_v<<<1, 128, 0, stream>>>(xp, bilW, v, 1.0f / (float)N);
    k_bil_out<<<(R + 127) / 128, 128, 0, stream>>>(v, y3, bilb, (float*)d_out, R);
  }
}